// Round 5
// baseline (201.529 us; speedup 1.0000x reference)
//
#include <hip/hip_runtime.h>
#include <math.h>

// [SQ, B, NP, HN] fp32, unscaled QK^T softmax attention.
#define SQ 2048
#define NBH 32           // B*NP heads
#define HN 64
#define BQ 64            // queries per block (2 waves x 32) -> grid 1024 = 4 blocks/CU
#define BK 64            // keys per tile
#define NT (SQ/BK)       // 32 key tiles
#define TOK 2048         // floats between consecutive tokens (B*NP*HN)
#define LDK 72           // padded LDS leading dim (144 B, 16B-divisible)

typedef _Float16 half2v __attribute__((ext_vector_type(2)));
typedef _Float16 half4v __attribute__((ext_vector_type(4)));
typedef _Float16 half8v __attribute__((ext_vector_type(8)));
typedef float f32x16 __attribute__((ext_vector_type(16)));

// Flash attention, S^T = K.Q^T via mfma_32x32x16_f16.
// 32x32 C layout: col = lane&31, row = (reg&3)+8*(reg>>2)+4*(lane>>5)
// => softmax state per-lane uniform; one shfl_xor(32) completes reductions.
// PV uses permuted k-order pi(h2,j) = 16ks + 4h2 + 8*(j>>2) + (j&3) so the
// P^T B-operand is exactly the C-layout registers packed pairwise.
// R4 lesson: compiler sinks register prefetch (VGPR stayed 68) -> single
// buffer; latency hidden by 4 independent blocks/CU instead.
__global__ __launch_bounds__(128, 2)
void fattn_mfma(const float* __restrict__ Q, const float* __restrict__ K,
                const float* __restrict__ V, float* __restrict__ O) {
  __shared__ __align__(16) _Float16 kb[BK][LDK];  // [key][dim] f16
  __shared__ __align__(16) _Float16 vt[HN][LDK];  // [dim][key] f16, 8-key blocks xor-swizzled by (dim>>3)&7

  const int t = threadIdx.x;        // 0..127
  const int lane = t & 63;
  const int w = t >> 6;             // wave 0..1
  const int h2 = lane >> 5;
  const int l31 = lane & 31;
  const int q0 = blockIdx.x * BQ + w * 32;
  const size_t hoff = (size_t)blockIdx.y * HN;

  // staging indices (128 threads stage the 64x64 K and V tiles)
  const int skey = t >> 1;          // K: key row 0..63
  const int shalf = t & 1;          // K: dim half (0..31 / 32..63)
  const int vm = t & 7;             // V: dim block
  const int vdb = vm * 8;
  const int vkp = (t >> 3) * 4;     // V: 4 consecutive keys
  const int vkeyS = vkp ^ (vm << 3);// xor-swizzle: position = key ^ (swz<<3)

  // ---- Q B-fragments, registers all kernel: n=query=l31, k=dim=8*h2+j+16*ks ----
  half8v qf[4];
  {
    const float* qp = Q + (size_t)(q0 + l31) * TOK + hoff + 8 * h2;
    #pragma unroll
    for (int ks = 0; ks < 4; ++ks) {
      float4 a = *(const float4*)(qp + 16 * ks);
      float4 b = *(const float4*)(qp + 16 * ks + 4);
      half8v f;
      f[0] = (_Float16)a.x; f[1] = (_Float16)a.y; f[2] = (_Float16)a.z; f[3] = (_Float16)a.w;
      f[4] = (_Float16)b.x; f[5] = (_Float16)b.y; f[6] = (_Float16)b.z; f[7] = (_Float16)b.w;
      qf[ks] = f;
    }
  }

  f32x16 acc0, acc1;   // O^T frags: dims 0..31, 32..63
  #pragma unroll
  for (int r = 0; r < 16; ++r) { acc0[r] = 0.f; acc1[r] = 0.f; }
  float m_i = -INFINITY, l_i = 0.f;

  for (int kt = 0; kt < SQ; kt += BK) {
    __syncthreads();   // previous tile's readers done
    // ---- stage K [key][dim] as f16: thread covers 32 dims of one key ----
    {
      const float* kp = K + (size_t)(kt + skey) * TOK + hoff + shalf * 32;
      #pragma unroll
      for (int i = 0; i < 4; ++i) {
        float4 a = *(const float4*)(kp + i * 8);
        float4 b = *(const float4*)(kp + i * 8 + 4);
        half8v h;
        h[0] = (_Float16)a.x; h[1] = (_Float16)a.y; h[2] = (_Float16)a.z; h[3] = (_Float16)a.w;
        h[4] = (_Float16)b.x; h[5] = (_Float16)b.y; h[6] = (_Float16)b.z; h[7] = (_Float16)b.w;
        *(half8v*)&kb[skey][shalf * 32 + i * 8] = h;
      }
    }
    // ---- stage V^T [dim][key] swizzled: thread covers 8 dims x 4 keys ----
    {
      const float* v0 = V + (size_t)(kt + vkp) * TOK + hoff + vdb;
      float4 r0a = *(const float4*)v0;
      float4 r0b = *(const float4*)(v0 + 4);
      float4 r1a = *(const float4*)(v0 + TOK);
      float4 r1b = *(const float4*)(v0 + TOK + 4);
      float4 r2a = *(const float4*)(v0 + 2 * TOK);
      float4 r2b = *(const float4*)(v0 + 2 * TOK + 4);
      float4 r3a = *(const float4*)(v0 + 3 * TOK);
      float4 r3b = *(const float4*)(v0 + 3 * TOK + 4);
      const float rv[4][8] = {
        {r0a.x, r0a.y, r0a.z, r0a.w, r0b.x, r0b.y, r0b.z, r0b.w},
        {r1a.x, r1a.y, r1a.z, r1a.w, r1b.x, r1b.y, r1b.z, r1b.w},
        {r2a.x, r2a.y, r2a.z, r2a.w, r2b.x, r2b.y, r2b.z, r2b.w},
        {r3a.x, r3a.y, r3a.z, r3a.w, r3b.x, r3b.y, r3b.z, r3b.w}};
      #pragma unroll
      for (int j = 0; j < 8; ++j) {
        half4v h;
        h[0] = (_Float16)rv[0][j]; h[1] = (_Float16)rv[1][j];
        h[2] = (_Float16)rv[2][j]; h[3] = (_Float16)rv[3][j];
        *(half4v*)&vt[vdb + j][vkeyS] = h;
      }
    }
    __syncthreads();

    // ---- S^T = K . Q^T ----
    f32x16 sf0, sf1;
    {
      f32x16 c0, c1;
      #pragma unroll
      for (int r = 0; r < 16; ++r) { c0[r] = 0.f; c1[r] = 0.f; }
      #pragma unroll
      for (int ks = 0; ks < 4; ++ks) {
        half8v a0v = *(const half8v*)&kb[l31][8 * h2 + 16 * ks];
        half8v a1v = *(const half8v*)&kb[l31 + 32][8 * h2 + 16 * ks];
        c0 = __builtin_amdgcn_mfma_f32_32x32x16_f16(a0v, qf[ks], c0, 0, 0, 0);
        c1 = __builtin_amdgcn_mfma_f32_32x32x16_f16(a1v, qf[ks], c1, 0, 0, 0);
      }
      sf0 = c0; sf1 = c1;
    }

    // ---- online softmax (query = l31; lane^32 holds the other 32 keys) ----
    float mx = -INFINITY;
    #pragma unroll
    for (int r = 0; r < 16; ++r) mx = fmaxf(mx, fmaxf(sf0[r], sf1[r]));
    mx = fmaxf(mx, __shfl_xor(mx, 32, 64));
    const float mnew = fmaxf(m_i, mx);
    const float alpha = __expf(m_i - mnew);   // 0 on first tile
    float rsum = 0.f;
    #pragma unroll
    for (int r = 0; r < 16; ++r) {
      float p0 = __expf(sf0[r] - mnew);
      float p1 = __expf(sf1[r] - mnew);
      sf0[r] = p0; sf1[r] = p1;
      rsum += p0 + p1;
    }
    rsum += __shfl_xor(rsum, 32, 64);
    l_i = l_i * alpha + rsum;
    m_i = mnew;
    #pragma unroll
    for (int r = 0; r < 16; ++r) { acc0[r] *= alpha; acc1[r] *= alpha; }

    // ---- PV: O^T += V^T . P^T, permuted k-order; P^T = C-layout regs packed ----
    #pragma unroll
    for (int ks = 0; ks < 4; ++ks) {
      const int rb = 8 * (ks & 1);
      const f32x16& s = (ks < 2) ? sf0 : sf1;
      union { half8v v8; half2v v2[4]; } pu;
      #pragma unroll
      for (int tt = 0; tt < 4; ++tt) {
        auto pk = __builtin_amdgcn_cvt_pkrtz(s[rb + 2 * tt], s[rb + 2 * tt + 1]);
        pu.v2[tt] = *(half2v*)&pk;
      }
      #pragma unroll
      for (int mbd = 0; mbd < 2; ++mbd) {
        const int dim = l31 + 32 * mbd;
        const int swz = (dim >> 3) & 7;
        union { half8v v8; half4v v4[2]; } au;
        au.v4[0] = *(const half4v*)&vt[dim][(((2 * ks)     ^ swz) * 8) + 4 * h2];
        au.v4[1] = *(const half4v*)&vt[dim][(((2 * ks + 1) ^ swz) * 8) + 4 * h2];
        if (mbd == 0)
          acc0 = __builtin_amdgcn_mfma_f32_32x32x16_f16(au.v8, pu.v8, acc0, 0, 0, 0);
        else
          acc1 = __builtin_amdgcn_mfma_f32_32x32x16_f16(au.v8, pu.v8, acc1, 0, 0, 0);
      }
    }
  }

  // ---- epilogue: O^T C-layout -> global; dim = (r&3)+8*(r>>2)+4*h2 (+32) ----
  const float invl = 1.f / l_i;
  float* orow = O + (size_t)(q0 + l31) * TOK + hoff;
  #pragma unroll
  for (int r = 0; r < 16; ++r) {
    const int d = (r & 3) + 8 * (r >> 2) + 4 * h2;
    orow[d]      = acc0[r] * invl;
    orow[d + 32] = acc1[r] * invl;
  }
}

extern "C" void kernel_launch(void* const* d_in, const int* in_sizes, int n_in,
                              void* d_out, int out_size, void* d_ws, size_t ws_size,
                              hipStream_t stream) {
  const float* Q = (const float*)d_in[0];
  const float* K = (const float*)d_in[1];
  const float* V = (const float*)d_in[2];
  float* O = (float*)d_out;
  dim3 grid(SQ / BQ, NBH);   // 32 x 32 = 1024 blocks = 4 blocks/CU
  dim3 block(128);
  fattn_mfma<<<grid, block, 0, stream>>>(Q, K, V, O);
}

// Round 6
// 159.694 us; speedup vs baseline: 1.2620x; 1.2620x over previous
//
#include <hip/hip_runtime.h>
#include <math.h>
#include <stdint.h>

// [SQ, B, NP, HN] fp32, unscaled QK^T softmax attention.
#define SQ 2048
#define NBH 32           // B*NP heads
#define HN 64
#define BQ 128           // queries per block (4 waves x 32)
#define BK 64            // keys per tile
#define NT (SQ/BK)       // 32 key tiles
#define TOK 2048         // floats between consecutive tokens (B*NP*HN)
#define HSTRIDE (SQ*HN)  // 131072 halfs per head in the f16 scratch layouts

typedef _Float16 half2v __attribute__((ext_vector_type(2)));
typedef _Float16 half4v __attribute__((ext_vector_type(4)));
typedef _Float16 half8v __attribute__((ext_vector_type(8)));
typedef float f32x16 __attribute__((ext_vector_type(16)));

__device__ __forceinline__ void async16(const void* g, void* l) {
  __builtin_amdgcn_global_load_lds(
      (const __attribute__((address_space(1))) void*)g,
      (__attribute__((address_space(3))) void*)l, 16, 0, 0);
}

// ---- prep: K fp32 [key][b,n,dim] -> Kh f16 [head][key][dim], 16B chunks
// xor-swizzled within each 128B row: chunk c (dims 8c..8c+7) stored at c^(key&7).
__global__ __launch_bounds__(256) void prep_k(const float* __restrict__ K,
                                              _Float16* __restrict__ Kh) {
  const int t = threadIdx.x;
  const int head = blockIdx.y;
  const int key = blockIdx.x * 64 + (t >> 2);
  const int c0 = (t & 3) * 2;
  const float* src = K + (size_t)key * TOK + head * HN + c0 * 8;
  float4 a = *(const float4*)src;
  float4 b = *(const float4*)(src + 4);
  float4 c = *(const float4*)(src + 8);
  float4 d = *(const float4*)(src + 12);
  half8v h0, h1;
  h0[0]=(_Float16)a.x; h0[1]=(_Float16)a.y; h0[2]=(_Float16)a.z; h0[3]=(_Float16)a.w;
  h0[4]=(_Float16)b.x; h0[5]=(_Float16)b.y; h0[6]=(_Float16)b.z; h0[7]=(_Float16)b.w;
  h1[0]=(_Float16)c.x; h1[1]=(_Float16)c.y; h1[2]=(_Float16)c.z; h1[3]=(_Float16)c.w;
  h1[4]=(_Float16)d.x; h1[5]=(_Float16)d.y; h1[6]=(_Float16)d.z; h1[7]=(_Float16)d.w;
  _Float16* row = Kh + (size_t)head * HSTRIDE + (size_t)key * 64;
  *(half8v*)&row[((c0    ) ^ (key & 7)) * 8] = h0;
  *(half8v*)&row[((c0 + 1) ^ (key & 7)) * 8] = h1;
}

// ---- prep: V fp32 -> Vt f16 [head][dim][key], 8B (4-key) units xor-swizzled
// within each 64-key tile: unit u (keys 4u..4u+3) stored at u^(dim&15).
__global__ __launch_bounds__(256) void prep_v(const float* __restrict__ V,
                                              _Float16* __restrict__ Vt) {
  __shared__ _Float16 vs[HN * 64];
  const int t = threadIdx.x;
  const int head = blockIdx.y;
  const int kt = blockIdx.x * 64;
  const int kl = (t >> 3) * 2;
  const int db = (t & 7) * 8;
  const float* src = V + (size_t)(kt + kl) * TOK + head * HN + db;
  float4 a0 = *(const float4*)src;
  float4 a1 = *(const float4*)(src + 4);
  float4 b0 = *(const float4*)(src + TOK);
  float4 b1 = *(const float4*)(src + TOK + 4);
  const float av[8] = {a0.x,a0.y,a0.z,a0.w,a1.x,a1.y,a1.z,a1.w};
  const float bv[8] = {b0.x,b0.y,b0.z,b0.w,b1.x,b1.y,b1.z,b1.w};
  const int u = kl >> 2;
  #pragma unroll
  for (int j = 0; j < 8; ++j) {
    const int dim = db + j;
    const int pos = u ^ (dim & 15);
    half2v h; h[0] = (_Float16)av[j]; h[1] = (_Float16)bv[j];
    *(half2v*)&vs[dim * 64 + pos * 4 + (kl & 3)] = h;
  }
  __syncthreads();
  const int dim = t >> 2;
  const int q = (t & 3) ^ (dim & 3);   // spread LDS bank groups
  const _Float16* srow = &vs[dim * 64 + q * 16];
  _Float16* drow = Vt + (size_t)head * HSTRIDE + (size_t)dim * SQ + kt + q * 16;
  *(half8v*)&drow[0] = *(const half8v*)&srow[0];
  *(half8v*)&drow[8] = *(const half8v*)&srow[8];
}

// ---- main: flash attention, S^T = K.Q^T via mfma_32x32x16_f16.
// C layout: col = lane&31, row = (reg&3)+8*(reg>>2)+4*(lane>>5).
// PV uses permuted k-order pi(h2,j)=16ks+4h2+8*(j>>2)+(j&3) so P^T stays in regs.
// Staging: double-buffered global_load_lds (async DMA), one barrier per tile.
__global__ __launch_bounds__(256, 2)
void fattn_mfma(const float* __restrict__ Q, const _Float16* __restrict__ Kh,
                const _Float16* __restrict__ Vt, float* __restrict__ O) {
  __shared__ __align__(16) _Float16 kbf[2][BK * 64];  // [buf][key][dim-swizzled]
  __shared__ __align__(16) _Float16 vtf[2][HN * 64];  // [buf][dim][key-swizzled]

  const int t = threadIdx.x;
  const int lane = t & 63;
  const int w = t >> 6;
  const int h2 = lane >> 5;
  const int l31 = lane & 31;
  const int q0 = blockIdx.x * BQ + w * 32;
  const int head = blockIdx.y;
  const _Float16* Kp = Kh + (size_t)head * HSTRIDE;
  const _Float16* Vp = Vt + (size_t)head * HSTRIDE;

  // ---- Q B-fragments, registers all kernel: n=query=l31, k=dim=8*h2+j+16*ks ----
  half8v qf[4];
  {
    const float* qp = Q + (size_t)(q0 + l31) * TOK + head * HN + 8 * h2;
    #pragma unroll
    for (int ks = 0; ks < 4; ++ks) {
      float4 a = *(const float4*)(qp + 16 * ks);
      float4 b = *(const float4*)(qp + 16 * ks + 4);
      half8v f;
      f[0] = (_Float16)a.x; f[1] = (_Float16)a.y; f[2] = (_Float16)a.z; f[3] = (_Float16)a.w;
      f[4] = (_Float16)b.x; f[5] = (_Float16)b.y; f[6] = (_Float16)b.z; f[7] = (_Float16)b.w;
      qf[ks] = f;
    }
  }

  f32x16 acc0, acc1;   // O^T frags: dims 0..31, 32..63
  #pragma unroll
  for (int r = 0; r < 16; ++r) { acc0[r] = 0.f; acc1[r] = 0.f; }
  float m_i = -INFINITY, l_i = 0.f;

  // async stage of tile `it` into buffer it&1 (4 x 16B per thread, no VALU)
  auto stage = [&](int it) {
    const int kt = it * BK;
    const int buf = it & 1;
    #pragma unroll
    for (int i = 0; i < 2; ++i) {
      const int off = w * 1024 + i * 512;            // wave-uniform half-offset
      async16(Kp + (size_t)kt * 64 + off + lane * 8, &kbf[buf][off]);
    }
    #pragma unroll
    for (int i = 0; i < 2; ++i) {
      const int off = w * 1024 + i * 512;
      const int eo = off + lane * 8;
      const int dim = eo >> 6, inner = eo & 63;
      async16(Vp + (size_t)dim * SQ + kt + inner, &vtf[buf][off]);
    }
  };

  stage(0);
  for (int it = 0; it < NT; ++it) {
    __syncthreads();              // drains vmcnt: buf[it&1] ready; prior readers done
    if (it + 1 < NT) stage(it + 1);   // overlaps the whole compute below
    const int cur = it & 1;

    // ---- S^T = K . Q^T ----
    f32x16 sf0, sf1;
    {
      f32x16 c0, c1;
      #pragma unroll
      for (int r = 0; r < 16; ++r) { c0[r] = 0.f; c1[r] = 0.f; }
      #pragma unroll
      for (int ks = 0; ks < 4; ++ks) {
        const int pos = ((h2 + 2 * ks) ^ (l31 & 7)) * 8;
        half8v a0v = *(const half8v*)&kbf[cur][l31 * 64 + pos];
        half8v a1v = *(const half8v*)&kbf[cur][(l31 + 32) * 64 + pos];
        c0 = __builtin_amdgcn_mfma_f32_32x32x16_f16(a0v, qf[ks], c0, 0, 0, 0);
        c1 = __builtin_amdgcn_mfma_f32_32x32x16_f16(a1v, qf[ks], c1, 0, 0, 0);
      }
      sf0 = c0; sf1 = c1;
    }

    // ---- online softmax (query = l31; lane^32 holds the other 32 keys) ----
    float mx = -INFINITY;
    #pragma unroll
    for (int r = 0; r < 16; ++r) mx = fmaxf(mx, fmaxf(sf0[r], sf1[r]));
    mx = fmaxf(mx, __shfl_xor(mx, 32, 64));
    const float mnew = fmaxf(m_i, mx);
    const float alpha = __expf(m_i - mnew);   // 0 on first tile
    float rsum = 0.f;
    #pragma unroll
    for (int r = 0; r < 16; ++r) {
      float p0 = __expf(sf0[r] - mnew);
      float p1 = __expf(sf1[r] - mnew);
      sf0[r] = p0; sf1[r] = p1;
      rsum += p0 + p1;
    }
    rsum += __shfl_xor(rsum, 32, 64);
    l_i = l_i * alpha + rsum;
    m_i = mnew;
    #pragma unroll
    for (int r = 0; r < 16; ++r) { acc0[r] *= alpha; acc1[r] *= alpha; }

    // ---- PV: O^T += V^T . P^T, permuted k-order; P^T = C-layout regs packed ----
    #pragma unroll
    for (int ks = 0; ks < 4; ++ks) {
      const int rb = 8 * (ks & 1);
      const f32x16& s = (ks < 2) ? sf0 : sf1;
      union { half8v v8; half2v v2[4]; } pu;
      #pragma unroll
      for (int tt = 0; tt < 4; ++tt) {
        auto pk = __builtin_amdgcn_cvt_pkrtz(s[rb + 2 * tt], s[rb + 2 * tt + 1]);
        pu.v2[tt] = *(half2v*)&pk;
      }
      #pragma unroll
      for (int mbd = 0; mbd < 2; ++mbd) {
        const int dim = l31 + 32 * mbd;
        const int sw = dim & 15;
        union { half8v v8; half4v v4[2]; } au;
        au.v4[0] = *(const half4v*)&vtf[cur][dim * 64 + ((4 * ks + h2)     ^ sw) * 4];
        au.v4[1] = *(const half4v*)&vtf[cur][dim * 64 + ((4 * ks + 2 + h2) ^ sw) * 4];
        if (mbd == 0)
          acc0 = __builtin_amdgcn_mfma_f32_32x32x16_f16(au.v8, pu.v8, acc0, 0, 0, 0);
        else
          acc1 = __builtin_amdgcn_mfma_f32_32x32x16_f16(au.v8, pu.v8, acc1, 0, 0, 0);
      }
    }
  }

  // ---- epilogue: O^T C-layout -> global; dim = (r&3)+8*(r>>2)+4*h2 (+32) ----
  const float invl = 1.f / l_i;
  float* orow = O + (size_t)(q0 + l31) * TOK + head * HN;
  #pragma unroll
  for (int r = 0; r < 16; ++r) {
    const int d = (r & 3) + 8 * (r >> 2) + 4 * h2;
    orow[d]      = acc0[r] * invl;
    orow[d + 32] = acc1[r] * invl;
  }
}

extern "C" void kernel_launch(void* const* d_in, const int* in_sizes, int n_in,
                              void* d_out, int out_size, void* d_ws, size_t ws_size,
                              hipStream_t stream) {
  const float* Q = (const float*)d_in[0];
  const float* K = (const float*)d_in[1];
  const float* V = (const float*)d_in[2];
  float* O = (float*)d_out;
  _Float16* Kh = (_Float16*)d_ws;                       // 8 MB
  _Float16* Vh = Kh + (size_t)NBH * HSTRIDE;            // 8 MB
  prep_k<<<dim3(SQ / 64, NBH), 256, 0, stream>>>(K, Kh);
  prep_v<<<dim3(SQ / 64, NBH), 256, 0, stream>>>(V, Vh);
  fattn_mfma<<<dim3(SQ / BQ, NBH), 256, 0, stream>>>(Q, Kh, Vh, O);
}

// Round 7
// 142.784 us; speedup vs baseline: 1.4114x; 1.1184x over previous
//
#include <hip/hip_runtime.h>
#include <math.h>
#include <stdint.h>

// [SQ, B, NP, HN] fp32, unscaled QK^T softmax attention.
#define SQ 2048
#define NBH 32           // B*NP heads
#define HN 64
#define BQ 128           // queries per block (4 waves x 32)
#define BK 64            // keys per MFMA tile
#define BK2 128          // keys per loop phase (2 tiles)
#define NP2 (SQ/BK2)     // 16 phases
#define TOK 2048         // floats between consecutive tokens (B*NP*HN)
#define HSTRIDE (SQ*HN)  // halfs per head in the f16 scratch layouts

typedef _Float16 half2v __attribute__((ext_vector_type(2)));
typedef _Float16 half4v __attribute__((ext_vector_type(4)));
typedef _Float16 half8v __attribute__((ext_vector_type(8)));
typedef float f32x16 __attribute__((ext_vector_type(16)));

__device__ __forceinline__ void async16(const void* g, void* l) {
  __builtin_amdgcn_global_load_lds(
      (const __attribute__((address_space(1))) void*)g,
      (__attribute__((address_space(3))) void*)l, 16, 0, 0);
}

__device__ __forceinline__ float fexp2(float x) {
#if __has_builtin(__builtin_amdgcn_exp2f)
  return __builtin_amdgcn_exp2f(x);
#else
  return exp2f(x);
#endif
}

// ---- prep (one launch): K -> Kh f16 [head][key][dim] (16B chunks xor-swizzled
// by key&7 within the 128B row); V -> Vt f16 [head][dim][key] (4-key units
// xor-swizzled by dim&15 within each 64-key tile).
__global__ __launch_bounds__(256) void prep_kv(const float* __restrict__ K,
                                               const float* __restrict__ V,
                                               _Float16* __restrict__ Kh,
                                               _Float16* __restrict__ Vt) {
  __shared__ _Float16 vs[HN * 64];
  const int t = threadIdx.x;
  const int head = blockIdx.y;
  // K part
  {
    const int key = blockIdx.x * 64 + (t >> 2);
    const int c0 = (t & 3) * 2;
    const float* src = K + (size_t)key * TOK + head * HN + c0 * 8;
    float4 a = *(const float4*)src;
    float4 b = *(const float4*)(src + 4);
    float4 c = *(const float4*)(src + 8);
    float4 d = *(const float4*)(src + 12);
    half8v h0, h1;
    h0[0]=(_Float16)a.x; h0[1]=(_Float16)a.y; h0[2]=(_Float16)a.z; h0[3]=(_Float16)a.w;
    h0[4]=(_Float16)b.x; h0[5]=(_Float16)b.y; h0[6]=(_Float16)b.z; h0[7]=(_Float16)b.w;
    h1[0]=(_Float16)c.x; h1[1]=(_Float16)c.y; h1[2]=(_Float16)c.z; h1[3]=(_Float16)c.w;
    h1[4]=(_Float16)d.x; h1[5]=(_Float16)d.y; h1[6]=(_Float16)d.z; h1[7]=(_Float16)d.w;
    _Float16* row = Kh + (size_t)head * HSTRIDE + (size_t)key * 64;
    *(half8v*)&row[((c0    ) ^ (key & 7)) * 8] = h0;
    *(half8v*)&row[((c0 + 1) ^ (key & 7)) * 8] = h1;
  }
  // V part
  {
    const int kt = blockIdx.x * 64;
    const int kl = (t >> 3) * 2;
    const int db = (t & 7) * 8;
    const float* src = V + (size_t)(kt + kl) * TOK + head * HN + db;
    float4 a0 = *(const float4*)src;
    float4 a1 = *(const float4*)(src + 4);
    float4 b0 = *(const float4*)(src + TOK);
    float4 b1 = *(const float4*)(src + TOK + 4);
    const float av[8] = {a0.x,a0.y,a0.z,a0.w,a1.x,a1.y,a1.z,a1.w};
    const float bv[8] = {b0.x,b0.y,b0.z,b0.w,b1.x,b1.y,b1.z,b1.w};
    const int u = kl >> 2;
    #pragma unroll
    for (int j = 0; j < 8; ++j) {
      const int dim = db + j;
      const int pos = u ^ (dim & 15);
      half2v h; h[0] = (_Float16)av[j]; h[1] = (_Float16)bv[j];
      *(half2v*)&vs[dim * 64 + pos * 4 + (kl & 3)] = h;
    }
    __syncthreads();
    const int dim = t >> 2;
    const int q = (t & 3) ^ (dim & 3);
    const _Float16* srow = &vs[dim * 64 + q * 16];
    _Float16* drow = Vt + (size_t)head * HSTRIDE + (size_t)dim * SQ + kt + q * 16;
    *(half8v*)&drow[0] = *(const half8v*)&srow[0];
    *(half8v*)&drow[8] = *(const half8v*)&srow[8];
  }
}

// ---- main: flash attention, S^T = K.Q^T via mfma_32x32x16_f16.
// C layout: col = lane&31, row = (reg&3)+8*(reg>>2)+4*(lane>>5).
// PV uses permuted k-order pi(h2,j)=16ks+4h2+8*(j>>2)+(j&3) so P^T stays in regs.
// 128-key phases: 2 independent S-chains (ILP), softmax fixed costs halved,
// one barrier per 128 keys. Q pre-scaled by log2(e) -> bare v_exp_f32.
__global__ __launch_bounds__(256, 2)
void fattn_mfma(const float* __restrict__ Q, const _Float16* __restrict__ Kh,
                const _Float16* __restrict__ Vt, float* __restrict__ O) {
  __shared__ __align__(16) _Float16 kbf[2][2 * BK * 64];  // [buf][2 tiles][key][dim-swz]
  __shared__ __align__(16) _Float16 vtf[2][2 * HN * 64];  // [buf][2 tiles][dim][key-swz]

  const int t = threadIdx.x;
  const int lane = t & 63;
  const int w = t >> 6;
  const int h2 = lane >> 5;
  const int l31 = lane & 31;
  const int q0 = blockIdx.x * BQ + w * 32;
  const int head = blockIdx.y;
  const _Float16* Kp = Kh + (size_t)head * HSTRIDE;
  const _Float16* Vp = Vt + (size_t)head * HSTRIDE;

  // ---- Q B-fragments x log2(e), registers all kernel ----
  half8v qf[4];
  {
    const float* qp = Q + (size_t)(q0 + l31) * TOK + head * HN + 8 * h2;
    const float s = 1.44269504088896f;
    #pragma unroll
    for (int ks = 0; ks < 4; ++ks) {
      float4 a = *(const float4*)(qp + 16 * ks);
      float4 b = *(const float4*)(qp + 16 * ks + 4);
      half8v f;
      f[0] = (_Float16)(s*a.x); f[1] = (_Float16)(s*a.y); f[2] = (_Float16)(s*a.z); f[3] = (_Float16)(s*a.w);
      f[4] = (_Float16)(s*b.x); f[5] = (_Float16)(s*b.y); f[6] = (_Float16)(s*b.z); f[7] = (_Float16)(s*b.w);
      qf[ks] = f;
    }
  }

  f32x16 acc0, acc1;   // O^T frags: dims 0..31, 32..63
  #pragma unroll
  for (int r = 0; r < 16; ++r) { acc0[r] = 0.f; acc1[r] = 0.f; }
  float m_i = -INFINITY, l_i = 0.f;

  // async stage of phase p (tiles 2p, 2p+1) into buffer p&1; pure DMA, no VALU.
  auto stage = [&](int p) {
    const int buf = p & 1;
    const size_t kt = (size_t)p * BK2;
    #pragma unroll
    for (int i = 0; i < 4; ++i) {                 // K pair: 16 KB contiguous
      const int off = w * 512 + i * 2048;
      async16(Kp + kt * 64 + off + lane * 8, &kbf[buf][off]);
    }
    #pragma unroll
    for (int tl = 0; tl < 2; ++tl)
      #pragma unroll
      for (int i = 0; i < 2; ++i) {
        const int off = w * 1024 + i * 512;
        const int eo = off + lane * 8;
        const int dim = eo >> 6, inner = eo & 63;
        async16(Vp + (size_t)dim * SQ + kt + tl * 64 + inner,
                &vtf[buf][tl * 4096 + off]);
      }
  };

  stage(0);
  for (int p = 0; p < NP2; ++p) {
    __syncthreads();                 // drains vmcnt: buf p&1 ready; prior readers done
    if (p + 1 < NP2) stage(p + 1);   // overlaps all compute below
    const int cur = p & 1;

    // ---- S^T = K . Q^T for both tiles (independent chains) ----
    f32x16 sa0, sa1, sb0, sb1;
    {
      f32x16 c0, c1, d0, d1;
      #pragma unroll
      for (int r = 0; r < 16; ++r) { c0[r]=0.f; c1[r]=0.f; d0[r]=0.f; d1[r]=0.f; }
      #pragma unroll
      for (int ks = 0; ks < 4; ++ks) {
        const int pos = ((h2 + 2 * ks) ^ (l31 & 7)) * 8;
        half8v a0v = *(const half8v*)&kbf[cur][l31 * 64 + pos];
        half8v a1v = *(const half8v*)&kbf[cur][(l31 + 32) * 64 + pos];
        half8v b0v = *(const half8v*)&kbf[cur][4096 + l31 * 64 + pos];
        half8v b1v = *(const half8v*)&kbf[cur][4096 + (l31 + 32) * 64 + pos];
        c0 = __builtin_amdgcn_mfma_f32_32x32x16_f16(a0v, qf[ks], c0, 0, 0, 0);
        c1 = __builtin_amdgcn_mfma_f32_32x32x16_f16(a1v, qf[ks], c1, 0, 0, 0);
        d0 = __builtin_amdgcn_mfma_f32_32x32x16_f16(b0v, qf[ks], d0, 0, 0, 0);
        d1 = __builtin_amdgcn_mfma_f32_32x32x16_f16(b1v, qf[ks], d1, 0, 0, 0);
      }
      sa0 = c0; sa1 = c1; sb0 = d0; sb1 = d1;
    }

    // ---- combined online softmax over 128 keys (log2 domain) ----
    float mx = -INFINITY;
    #pragma unroll
    for (int r = 0; r < 16; ++r)
      mx = fmaxf(mx, fmaxf(fmaxf(sa0[r], sa1[r]), fmaxf(sb0[r], sb1[r])));
    mx = fmaxf(mx, __shfl_xor(mx, 32, 64));
    const float mnew = fmaxf(m_i, mx);
    const float alpha = fexp2(m_i - mnew);   // 0 on first phase
    float rsum = 0.f;
    #pragma unroll
    for (int r = 0; r < 16; ++r) {
      float p0 = fexp2(sa0[r] - mnew);
      float p1 = fexp2(sa1[r] - mnew);
      float p2 = fexp2(sb0[r] - mnew);
      float p3 = fexp2(sb1[r] - mnew);
      sa0[r] = p0; sa1[r] = p1; sb0[r] = p2; sb1[r] = p3;
      rsum += (p0 + p1) + (p2 + p3);
    }
    rsum += __shfl_xor(rsum, 32, 64);
    l_i = l_i * alpha + rsum;
    m_i = mnew;
    #pragma unroll
    for (int r = 0; r < 16; ++r) { acc0[r] *= alpha; acc1[r] *= alpha; }

    // ---- PV for both tiles: O^T += V^T . P^T, permuted k-order ----
    #pragma unroll
    for (int tl = 0; tl < 2; ++tl) {
      const int vbase = tl * 4096;
      #pragma unroll
      for (int ks = 0; ks < 4; ++ks) {
        const int rb = 8 * (ks & 1);
        const f32x16& s = tl ? ((ks < 2) ? sb0 : sb1) : ((ks < 2) ? sa0 : sa1);
        union { half8v v8; half2v v2[4]; } pu;
        #pragma unroll
        for (int tt = 0; tt < 4; ++tt) {
          auto pk = __builtin_amdgcn_cvt_pkrtz(s[rb + 2 * tt], s[rb + 2 * tt + 1]);
          pu.v2[tt] = *(half2v*)&pk;
        }
        #pragma unroll
        for (int mbd = 0; mbd < 2; ++mbd) {
          const int dim = l31 + 32 * mbd;
          const int sw = dim & 15;
          union { half8v v8; half4v v4[2]; } au;
          au.v4[0] = *(const half4v*)&vtf[cur][vbase + dim * 64 + ((4 * ks + h2)     ^ sw) * 4];
          au.v4[1] = *(const half4v*)&vtf[cur][vbase + dim * 64 + ((4 * ks + 2 + h2) ^ sw) * 4];
          if (mbd == 0)
            acc0 = __builtin_amdgcn_mfma_f32_32x32x16_f16(au.v8, pu.v8, acc0, 0, 0, 0);
          else
            acc1 = __builtin_amdgcn_mfma_f32_32x32x16_f16(au.v8, pu.v8, acc1, 0, 0, 0);
        }
      }
    }
  }

  // ---- epilogue: O^T C-layout -> global; dim = (r&3)+8*(r>>2)+4*h2 (+32) ----
  const float invl = 1.f / l_i;
  float* orow = O + (size_t)(q0 + l31) * TOK + head * HN;
  #pragma unroll
  for (int r = 0; r < 16; ++r) {
    const int d = (r & 3) + 8 * (r >> 2) + 4 * h2;
    orow[d]      = acc0[r] * invl;
    orow[d + 32] = acc1[r] * invl;
  }
}

extern "C" void kernel_launch(void* const* d_in, const int* in_sizes, int n_in,
                              void* d_out, int out_size, void* d_ws, size_t ws_size,
                              hipStream_t stream) {
  const float* Q = (const float*)d_in[0];
  const float* K = (const float*)d_in[1];
  const float* V = (const float*)d_in[2];
  float* O = (float*)d_out;
  _Float16* Kh = (_Float16*)d_ws;                       // 8 MB
  _Float16* Vh = Kh + (size_t)NBH * HSTRIDE;            // 8 MB
  prep_kv<<<dim3(SQ / 64, NBH), 256, 0, stream>>>(K, V, Kh, Vh);
  fattn_mfma<<<dim3(SQ / BQ, NBH), 256, 0, stream>>>(Q, Kh, Vh, O);
}